// Round 1
// baseline (237.277 us; speedup 1.0000x reference)
//
#include <hip/hip_runtime.h>
#include <hip/hip_bf16.h>
#include <stdint.h>

#define IC 32
#define OC 32
#define HID 32
#define NPIECE 33   // piece index c in [0,32]

typedef __attribute__((ext_vector_type(8))) short short8;
typedef __attribute__((ext_vector_type(4))) float f32x4;

static __device__ __forceinline__ short f2bf(float f) {
    __bf16 b = (__bf16)f;
    return __builtin_bit_cast(short, b);
}

// ---------------------------------------------------------------------------
// Zero-init output (fallback path only; main path writes out fully in gather)
// ---------------------------------------------------------------------------
__global__ void zero_kernel(float* __restrict__ out, int n) {
    int i = (blockIdx.x * blockDim.x + threadIdx.x) * 4;
    if (i + 3 < n) {
        *(float4*)(out + i) = make_float4(0.f, 0.f, 0.f, 0.f);
    } else {
        for (int k = i; k < n; ++k) out[k] = 0.f;
    }
}

// ---------------------------------------------------------------------------
// Edge branch (unchanged structure):
//   Z(E x 1056) @ W2r(1056 x 32) via mfma_f32_16x16x32_bf16, scatter-atomic.
// ---------------------------------------------------------------------------
__global__ __launch_bounds__(256) void edge_kernel(
    const float* __restrict__ x, const int* __restrict__ edge_index,
    const float* __restrict__ edge_attr,
    const float* __restrict__ eW1, const float* __restrict__ eb1,
    const float* __restrict__ eW2, const float* __restrict__ eb2,
    float* __restrict__ out, int E)
{
    const int tid   = threadIdx.x;
    const int lane  = tid & 63;
    const int gwave = blockIdx.x * 4 + (tid >> 6);
    const int ot    = gwave & 1;            // which 16-wide output tile
    const int tile0 = gwave >> 1;
    const int tstride = (gridDim.x * 4) >> 1;
    const int q     = lane >> 4;
    const int l15   = lane & 15;
    const int ocol  = ot * 16 + l15;

    // --- load B fragments once (register-resident across all edge tiles) ---
    short8 Bf[33];
#pragma unroll
    for (int s = 0; s < 32; ++s) {
        short8 b;
#pragma unroll
        for (int j = 0; j < 8; ++j)
            b[j] = f2bf(eW2[s * 1024 + (q * 8 + j) * 32 + ocol]);
        Bf[s] = b;
    }
    {
        short8 b;
#pragma unroll
        for (int j = 0; j < 8; ++j)
            b[j] = f2bf(eb2[(q * 8 + j) * 32 + ocol]);
        Bf[32] = b;
    }

    const int numTiles = (E + 15) >> 4;
    for (int tile = tile0; tile < numTiles; tile += tstride) {
        const int e16 = tile << 4;
        const int eA  = e16 + l15;
        const bool va = (eA < E);
        const int eAc = va ? eA : 0;
        const float t = va ? edge_attr[eAc] : 0.f;
        const int col = va ? edge_index[E + eAc] : 0;

        const float* xp = x + col * IC + q * 8;
        const float4 xlo = *(const float4*)(xp);
        const float4 xhi = *(const float4*)(xp + 4);
        float xf[8] = {xlo.x, xlo.y, xlo.z, xlo.w, xhi.x, xhi.y, xhi.z, xhi.w};

        f32x4 acc = {0.f, 0.f, 0.f, 0.f};
#pragma unroll
        for (int s = 0; s < 32; ++s) {
            float hs = t * eW1[s] + eb1[s];
            hs = hs > 0.f ? hs : 0.f;
            short8 a;
#pragma unroll
            for (int j = 0; j < 8; ++j) a[j] = f2bf(xf[j] * hs);
            acc = __builtin_amdgcn_mfma_f32_16x16x32_bf16(a, Bf[s], acc, 0, 0, 0);
        }
        {   // bias K-step
            short8 a;
#pragma unroll
            for (int j = 0; j < 8; ++j) a[j] = f2bf(xf[j]);
            acc = __builtin_amdgcn_mfma_f32_16x16x32_bf16(a, Bf[32], acc, 0, 0, 0);
        }

        const int ebase = e16 + q * 4;
#pragma unroll
        for (int r = 0; r < 4; ++r) {
            const int er = ebase + r;
            if (er < E) {
                const int dst = edge_index[er];
                unsafeAtomicAdd(out + dst * OC + ocol, acc[r]);
            }
        }
    }
}

// ---------------------------------------------------------------------------
// Angle branch, stage 1: classify each angle onto its linear piece and
// accumulate (count, sum-of-t) per (node, piece) cell. 2 atomics per angle
// instead of 32.
// Piece id c(t) = # hinges in their "t=+inf" state: monotone in t, and
// equal c  =>  same relu mask  =>  feat() is linear over the group.
// ---------------------------------------------------------------------------
__global__ __launch_bounds__(256) void angle_scatter(
    const float* __restrict__ angles, const int* __restrict__ angle_index,
    const float* __restrict__ aW1, const float* __restrict__ ab1,
    float* __restrict__ cnt_ws, float* __restrict__ tsum_ws, int A)
{
    float w1[HID], b1[HID];
#pragma unroll
    for (int k = 0; k < HID; ++k) { w1[k] = aW1[k]; b1[k] = ab1[k]; }

    int i0 = blockIdx.x * blockDim.x + threadIdx.x;
    int stride = gridDim.x * blockDim.x;
    for (int a = i0; a < A; a += stride) {
        const float t = angles[a];
        const int j = angle_index[A + a];   // center node
        int c = 0;
#pragma unroll
        for (int k = 0; k < HID; ++k) {
            const float pre = fmaf(t, w1[k], b1[k]);
            const bool on = pre > 0.f;
            const bool flip = (w1[k] > 0.f) ? on : !on;
            c += flip ? 1 : 0;
        }
        const int base = j * NPIECE + c;
        unsafeAtomicAdd(cnt_ws + base, 1.f);
        unsafeAtomicAdd(tsum_ws + base, t);
    }
}

// ---------------------------------------------------------------------------
// Angle branch, stage 2: per node, for each nonempty (node,piece) cell,
//   contribution = cnt * feat(tsum/cnt)    (exact: feat linear on the piece;
//   the mean of a group stays inside the piece interval, so the relu mask
//   evaluated at the mean is the group's mask).
// 2 nodes per wave (32 lanes = 32 output channels each). Writes out fully
// (replaces zero_kernel): edge_kernel's atomics run after this in-stream.
// Only c in [c(0), c(1)] can be realized for t in [0,1) -> short loop.
// ---------------------------------------------------------------------------
__global__ __launch_bounds__(256) void angle_gather(
    const float* __restrict__ cnt_ws, const float* __restrict__ tsum_ws,
    const float* __restrict__ aW1, const float* __restrict__ ab1,
    const float* __restrict__ aW2, const float* __restrict__ ab2,
    float* __restrict__ out, int N)
{
    const int lane = threadIdx.x & 63;
    const int o    = lane & 31;
    const int half = lane >> 5;
    const int wib  = threadIdx.x >> 6;        // wave in block
    const int gw   = blockIdx.x * (blockDim.x >> 6) + wib;
    const int nodesPerIter = gridDim.x * (blockDim.x >> 6) * 2;

    float w1[HID], b1[HID], w2[HID];
#pragma unroll
    for (int k = 0; k < HID; ++k) {
        w1[k] = aW1[k];
        b1[k] = ab1[k];
        w2[k] = aW2[k * OC + o];
    }
    const float bias = ab2[o];

    // realized piece-index range for t in [0,1):  c(0) .. c(1)
    int c0 = 0, c1 = 0;
#pragma unroll
    for (int k = 0; k < HID; ++k) {
        const bool pos = w1[k] > 0.f;
        const bool f0 = pos ? (b1[k] > 0.f) : !(b1[k] > 0.f);
        const bool f1 = pos ? (fmaf(1.f, w1[k], b1[k]) > 0.f)
                            : !(fmaf(1.f, w1[k], b1[k]) > 0.f);
        c0 += f0 ? 1 : 0;
        c1 += f1 ? 1 : 0;
    }

    for (int j = gw * 2 + half; j < N; j += nodesPerIter) {
        const float* cj = cnt_ws + j * NPIECE;
        const float* tj = tsum_ws + j * NPIECE;
        float acc = 0.f, tot = 0.f;
        for (int c = c0; c <= c1; ++c) {
            const float n = cj[c];
            if (n != 0.f) {
                const float t = tj[c] / n;
                float s = 0.f;
#pragma unroll
                for (int k = 0; k < HID; ++k) {
                    float h = fmaf(t, w1[k], b1[k]);
                    h = h > 0.f ? h : 0.f;
                    s = fmaf(h, w2[k], s);
                }
                acc = fmaf(n, s, acc);
                tot += n;
            }
        }
        out[j * OC + o] = fmaf(tot, bias, acc);   // full overwrite of out
    }
}

// ---------------------------------------------------------------------------
// Fallback angle kernel (old path) if workspace is too small.
// ---------------------------------------------------------------------------
__global__ __launch_bounds__(256) void angle_kernel(
    const float* __restrict__ angles, const int* __restrict__ angle_index,
    const float* __restrict__ aW1, const float* __restrict__ ab1,
    const float* __restrict__ aW2, const float* __restrict__ ab2,
    float* __restrict__ out, int A)
{
    const int tid   = threadIdx.x;
    const int lane  = tid & 63;
    const int gwave = blockIdx.x * 4 + (tid >> 6);
    const int ot    = gwave & 1;
    const int tile0 = gwave >> 1;
    const int tstride = (gridDim.x * 4) >> 1;
    const int q     = lane >> 4;
    const int l15   = lane & 15;
    const int ocol  = ot * 16 + l15;

    short8 Bf;
#pragma unroll
    for (int j = 0; j < 8; ++j)
        Bf[j] = f2bf(aW2[(q * 8 + j) * 32 + ocol]);
    const float bias = ab2[ocol];

    float w1[8], b1[8];
#pragma unroll
    for (int j = 0; j < 8; ++j) {
        w1[j] = aW1[q * 8 + j];
        b1[j] = ab1[q * 8 + j];
    }

    const int numTiles = (A + 15) >> 4;
    for (int tile = tile0; tile < numTiles; tile += tstride) {
        const int a16 = tile << 4;
        const int ai  = a16 + l15;
        const float t = (ai < A) ? angles[ai] : 0.f;

        short8 a;
#pragma unroll
        for (int j = 0; j < 8; ++j) {
            float h = t * w1[j] + b1[j];
            h = h > 0.f ? h : 0.f;
            a[j] = f2bf(h);
        }
        f32x4 acc = {0.f, 0.f, 0.f, 0.f};
        acc = __builtin_amdgcn_mfma_f32_16x16x32_bf16(a, Bf, acc, 0, 0, 0);

        const int abase = a16 + q * 4;
#pragma unroll
        for (int r = 0; r < 4; ++r) {
            const int ar = abase + r;
            if (ar < A) {
                const int dst = angle_index[A + ar];
                unsafeAtomicAdd(out + dst * OC + ocol, acc[r] + bias);
            }
        }
    }
}

// ---------------------------------------------------------------------------
extern "C" void kernel_launch(void* const* d_in, const int* in_sizes, int n_in,
                              void* d_out, int out_size, void* d_ws, size_t ws_size,
                              hipStream_t stream)
{
    const float* x          = (const float*)d_in[0];
    const int*   edge_index = (const int*)d_in[1];
    const float* edge_attr  = (const float*)d_in[2];
    const int*   angle_index= (const int*)d_in[3];
    const float* angles     = (const float*)d_in[4];
    const float* eW1        = (const float*)d_in[5];
    const float* eb1        = (const float*)d_in[6];
    const float* eW2        = (const float*)d_in[7];
    const float* eb2        = (const float*)d_in[8];
    const float* aW1        = (const float*)d_in[9];
    const float* ab1        = (const float*)d_in[10];
    const float* aW2        = (const float*)d_in[11];
    const float* ab2        = (const float*)d_in[12];
    float* out = (float*)d_out;

    const int E = in_sizes[1] / 2;
    const int A = in_sizes[3] / 3;
    const int N = in_sizes[0] / IC;

    const size_t cells = (size_t)N * NPIECE;
    const size_t need  = cells * 2 * sizeof(float);

    if (d_ws && ws_size >= need) {
        float* cnt_ws  = (float*)d_ws;
        float* tsum_ws = cnt_ws + cells;

        hipMemsetAsync(d_ws, 0, need, stream);

        const int sblocks = (A + 255) / 256;
        angle_scatter<<<sblocks, 256, 0, stream>>>(angles, angle_index,
                                                   aW1, ab1, cnt_ws, tsum_ws, A);

        // writes every element of out (replaces zero_kernel)
        angle_gather<<<2048, 256, 0, stream>>>(cnt_ws, tsum_ws,
                                               aW1, ab1, aW2, ab2, out, N);

        edge_kernel<<<1024, 256, 0, stream>>>(x, edge_index, edge_attr,
                                              eW1, eb1, eW2, eb2, out, E);
    } else {
        // fallback: original path
        const int zblocks = (out_size / 4 + 255) / 256;
        zero_kernel<<<zblocks, 256, 0, stream>>>(out, out_size);
        edge_kernel<<<1024, 256, 0, stream>>>(x, edge_index, edge_attr,
                                              eW1, eb1, eW2, eb2, out, E);
        angle_kernel<<<512, 256, 0, stream>>>(angles, angle_index,
                                              aW1, ab1, aW2, ab2, out, A);
    }
}

// Round 2
// 226.234 us; speedup vs baseline: 1.0488x; 1.0488x over previous
//
#include <hip/hip_runtime.h>
#include <hip/hip_bf16.h>
#include <stdint.h>

#define IC 32
#define OC 32
#define HID 32

// Angle binning: per node, PBIN u64 cells of (count << TSH | sum of t*2^20),
// stored IN-PLACE in the output buffer (one node row = 32 floats = 16 u64).
// count field: 20 bits (max 1M >= A=400k, safe for any index distribution).
// t-sum field: 44 bits (max A * 2^20 = 2^38.6 < 2^44, overflow impossible).
#define PBIN 16
#define TSH 44
#define TSCALE 1048576.0f   // 2^20

typedef __attribute__((ext_vector_type(8))) short short8;
typedef __attribute__((ext_vector_type(4))) float f32x4;
typedef unsigned long long u64;

static __device__ __forceinline__ short f2bf(float f) {
    __bf16 b = (__bf16)f;
    return __builtin_bit_cast(short, b);
}

// ---------------------------------------------------------------------------
// Zero-init output (also clears the in-place binning cells)
// ---------------------------------------------------------------------------
__global__ void zero_kernel(float* __restrict__ out, int n) {
    int i = (blockIdx.x * blockDim.x + threadIdx.x) * 4;
    if (i + 3 < n) {
        *(float4*)(out + i) = make_float4(0.f, 0.f, 0.f, 0.f);
    } else {
        for (int k = i; k < n; ++k) out[k] = 0.f;
    }
}

// ---------------------------------------------------------------------------
// Angle stage 1: classify each angle onto its linear piece of
//   feat(t) = relu(t*aW1 + ab1) @ aW2 + ab2   (piecewise-linear in scalar t)
// Piece id c(t) = # hinges in their t->+inf state (monotone in t; equal c
// => identical relu mask => feat linear over the group). Accumulate
// (count, sum-of-t) per (node, piece) with ONE u64 atomic per angle,
// directly into out[] reinterpreted as u64 cells (cleared by zero_kernel).
// cc = c - c(0) is in [0, numPieces); pieces >= PBIN handled by fixup.
// ---------------------------------------------------------------------------
__global__ __launch_bounds__(256) void angle_scatter(
    const float* __restrict__ angles, const int* __restrict__ angle_index,
    const float* __restrict__ aW1, const float* __restrict__ ab1,
    u64* __restrict__ cells, int A)
{
    float w1[HID], b1[HID];
#pragma unroll
    for (int k = 0; k < HID; ++k) { w1[k] = aW1[k]; b1[k] = ab1[k]; }

    int i0 = blockIdx.x * blockDim.x + threadIdx.x;
    int stride = gridDim.x * blockDim.x;
    for (int a = i0; a < A; a += stride) {
        const float t = angles[a];
        const int j = angle_index[A + a];   // center node
        int c = 0, c0 = 0;
#pragma unroll
        for (int k = 0; k < HID; ++k) {
            const bool pos = w1[k] > 0.f;
            const bool on  = fmaf(t, w1[k], b1[k]) > 0.f;
            const bool on0 = b1[k] > 0.f;
            c  += (pos ? on  : !on ) ? 1 : 0;
            c0 += (pos ? on0 : !on0) ? 1 : 0;
        }
        const int cc = c - c0;
        if ((unsigned)cc < (unsigned)PBIN) {
            const u64 enc = ((u64)1 << TSH) | (u64)(unsigned)(t * TSCALE);
            atomicAdd(cells + (size_t)j * PBIN + cc, enc);
        }
        // cc >= PBIN (requires >16 realized pieces) handled by angle_fixup
    }
}

// ---------------------------------------------------------------------------
// Angle stage 2: per node, decode its 16 cells and evaluate
//   sum_pieces cnt * feat(tsum/cnt)    (exact: feat is linear on the piece,
//   and the group mean stays inside the piece interval, so the relu mask at
//   the mean equals the group's mask).
// 2 nodes per wave (32 lanes = 32 output channels). Reads the node's own
// row as u64, then OVERWRITES it with the fp32 result (in-wave ordering
// makes the in-place swap safe; each row is touched by exactly one wave).
// ---------------------------------------------------------------------------
__global__ __launch_bounds__(256) void angle_gather(
    float* __restrict__ out,
    const float* __restrict__ aW1, const float* __restrict__ ab1,
    const float* __restrict__ aW2, const float* __restrict__ ab2,
    int N)
{
    const int lane = threadIdx.x & 63;
    const int o    = lane & 31;
    const int half = lane >> 5;
    const int wib  = threadIdx.x >> 6;
    const int gw   = blockIdx.x * (blockDim.x >> 6) + wib;
    const int nodesPerIter = gridDim.x * (blockDim.x >> 6) * 2;

    float w1[HID], b1[HID], w2[HID];
#pragma unroll
    for (int k = 0; k < HID; ++k) {
        w1[k] = aW1[k];
        b1[k] = ab1[k];
        w2[k] = aW2[k * OC + o];
    }
    const float bias = ab2[o];

    for (int j = gw * 2 + half; j < N; j += nodesPerIter) {
        const u64* cj = (const u64*)out + (size_t)j * PBIN;
        float acc = 0.f, tot = 0.f;
#pragma unroll
        for (int cc = 0; cc < PBIN; ++cc) {
            const u64 v = cj[cc];
            if (v) {
                const float n  = (float)(unsigned)(v >> TSH);
                const float ts = (float)(v & (((u64)1 << TSH) - 1)) * (1.f / TSCALE);
                const float tb = ts / n;
                float s = 0.f;
#pragma unroll
                for (int k = 0; k < HID; ++k) {
                    float h = fmaf(tb, w1[k], b1[k]);
                    h = h > 0.f ? h : 0.f;
                    s = fmaf(h, w2[k], s);
                }
                acc = fmaf(n, s, acc);
                tot += n;
            }
        }
        out[(size_t)j * OC + o] = fmaf(tot, bias, acc);
    }
}

// ---------------------------------------------------------------------------
// Fixup for angles whose piece index exceeds PBIN (only possible if the
// weight draw realizes >16 pieces on t in [0,1); expected ZERO work --
// uniform early-exit). Runs AFTER gather, adds exact feat via atomics.
// ---------------------------------------------------------------------------
__global__ __launch_bounds__(256) void angle_fixup(
    const float* __restrict__ angles, const int* __restrict__ angle_index,
    const float* __restrict__ aW1, const float* __restrict__ ab1,
    const float* __restrict__ aW2, const float* __restrict__ ab2,
    float* __restrict__ out, int A)
{
    float w1[HID], b1[HID];
#pragma unroll
    for (int k = 0; k < HID; ++k) { w1[k] = aW1[k]; b1[k] = ab1[k]; }

    int c0 = 0, c1 = 0;
#pragma unroll
    for (int k = 0; k < HID; ++k) {
        const bool pos = w1[k] > 0.f;
        const bool f0 = pos ? (b1[k] > 0.f) : !(b1[k] > 0.f);
        const bool f1 = pos ? ((w1[k] + b1[k]) > 0.f) : !((w1[k] + b1[k]) > 0.f);
        c0 += f0 ? 1 : 0;
        c1 += f1 ? 1 : 0;
    }
    if (c1 - c0 + 1 <= PBIN) return;   // uniform: no overflow possible

    int i0 = blockIdx.x * blockDim.x + threadIdx.x;
    int stride = gridDim.x * blockDim.x;
    for (int a = i0; a < A; a += stride) {
        const float t = angles[a];
        const int j = angle_index[A + a];
        int c = 0;
#pragma unroll
        for (int k = 0; k < HID; ++k) {
            const bool pos = w1[k] > 0.f;
            const bool on  = fmaf(t, w1[k], b1[k]) > 0.f;
            c += (pos ? on : !on) ? 1 : 0;
        }
        if (c - c0 >= PBIN) {
            float h[HID];
#pragma unroll
            for (int k = 0; k < HID; ++k) {
                float v = fmaf(t, w1[k], b1[k]);
                h[k] = v > 0.f ? v : 0.f;
            }
            for (int o = 0; o < OC; ++o) {
                float s = ab2[o];
#pragma unroll
                for (int k = 0; k < HID; ++k) s = fmaf(h[k], aW2[k * OC + o], s);
                unsafeAtomicAdd(out + (size_t)j * OC + o, s);
            }
        }
    }
}

// ---------------------------------------------------------------------------
// Edge branch:
//   Z(E x 1056) @ W2r(1056 x 32) via mfma_f32_16x16x32_bf16, scatter-atomic.
// Latency-bound at ~2 waves/SIMD (grid 512: measured better than 1024) ->
// 1-deep software pipeline: prefetch next tile's (t, col, x[col]) dependent
// load chain and this tile's 4 scatter row indices before the MFMA loop.
// ---------------------------------------------------------------------------
__global__ __launch_bounds__(256) void edge_kernel(
    const float* __restrict__ x, const int* __restrict__ edge_index,
    const float* __restrict__ edge_attr,
    const float* __restrict__ eW1, const float* __restrict__ eb1,
    const float* __restrict__ eW2, const float* __restrict__ eb2,
    float* __restrict__ out, int E)
{
    const int tid   = threadIdx.x;
    const int lane  = tid & 63;
    const int gwave = blockIdx.x * 4 + (tid >> 6);
    const int ot    = gwave & 1;            // which 16-wide output tile
    const int tile0 = gwave >> 1;
    const int tstride = (gridDim.x * 4) >> 1;
    const int q     = lane >> 4;
    const int l15   = lane & 15;
    const int ocol  = ot * 16 + l15;

    // --- load B fragments once (register-resident across all edge tiles) ---
    short8 Bf[33];
#pragma unroll
    for (int s = 0; s < 32; ++s) {
        short8 b;
#pragma unroll
        for (int j = 0; j < 8; ++j)
            b[j] = f2bf(eW2[s * 1024 + (q * 8 + j) * 32 + ocol]);
        Bf[s] = b;
    }
    {
        short8 b;
#pragma unroll
        for (int j = 0; j < 8; ++j)
            b[j] = f2bf(eb2[(q * 8 + j) * 32 + ocol]);
        Bf[32] = b;
    }

    const int numTiles = (E + 15) >> 4;
    int tile = tile0;
    if (tile >= numTiles) return;

    // pipeline stage: current tile's inputs
    float t; float4 xlo, xhi;
    {
        const int eA = (tile << 4) + l15;
        const bool va = eA < E;
        const int eAc = va ? eA : 0;
        t = va ? edge_attr[eAc] : 0.f;
        const int col = va ? edge_index[E + eAc] : 0;
        const float* xp = x + col * IC + q * 8;
        xlo = *(const float4*)xp;
        xhi = *(const float4*)(xp + 4);
    }

    while (true) {
        // ---- prefetch next tile (overlaps with this tile's compute) ----
        const int nt = tile + tstride;
        const bool have2 = nt < numTiles;
        float t2 = 0.f; float4 xlo2 = {0,0,0,0}, xhi2 = {0,0,0,0};
        if (have2) {
            const int eA = (nt << 4) + l15;
            const bool va = eA < E;
            const int eAc = va ? eA : 0;
            t2 = va ? edge_attr[eAc] : 0.f;
            const int col2 = va ? edge_index[E + eAc] : 0;
            const float* xp = x + col2 * IC + q * 8;
            xlo2 = *(const float4*)xp;
            xhi2 = *(const float4*)(xp + 4);
        }
        // hoist scatter row indices (latency hides under MFMA loop)
        const int ebase = (tile << 4) + q * 4;
        int dsts[4];
#pragma unroll
        for (int r = 0; r < 4; ++r) {
            const int er = ebase + r;
            dsts[r] = (er < E) ? edge_index[er] : -1;
        }

        const float xf[8] = {xlo.x, xlo.y, xlo.z, xlo.w,
                             xhi.x, xhi.y, xhi.z, xhi.w};
        f32x4 acc = {0.f, 0.f, 0.f, 0.f};
#pragma unroll
        for (int s = 0; s < 32; ++s) {
            float hs = t * eW1[s] + eb1[s];
            hs = hs > 0.f ? hs : 0.f;
            short8 a;
#pragma unroll
            for (int j = 0; j < 8; ++j) a[j] = f2bf(xf[j] * hs);
            acc = __builtin_amdgcn_mfma_f32_16x16x32_bf16(a, Bf[s], acc, 0, 0, 0);
        }
        {   // bias K-step (h == 1): adds sum_i x_i * eb2[i*32+o]
            short8 a;
#pragma unroll
            for (int j = 0; j < 8; ++j) a[j] = f2bf(xf[j]);
            acc = __builtin_amdgcn_mfma_f32_16x16x32_bf16(a, Bf[32], acc, 0, 0, 0);
        }

#pragma unroll
        for (int r = 0; r < 4; ++r) {
            if (dsts[r] >= 0)
                unsafeAtomicAdd(out + (size_t)dsts[r] * OC + ocol, acc[r]);
        }

        if (!have2) break;
        tile = nt; t = t2; xlo = xlo2; xhi = xhi2;
    }
}

// ---------------------------------------------------------------------------
extern "C" void kernel_launch(void* const* d_in, const int* in_sizes, int n_in,
                              void* d_out, int out_size, void* d_ws, size_t ws_size,
                              hipStream_t stream)
{
    const float* x          = (const float*)d_in[0];
    const int*   edge_index = (const int*)d_in[1];
    const float* edge_attr  = (const float*)d_in[2];
    const int*   angle_index= (const int*)d_in[3];
    const float* angles     = (const float*)d_in[4];
    const float* eW1        = (const float*)d_in[5];
    const float* eb1        = (const float*)d_in[6];
    const float* eW2        = (const float*)d_in[7];
    const float* eb2        = (const float*)d_in[8];
    const float* aW1        = (const float*)d_in[9];
    const float* ab1        = (const float*)d_in[10];
    const float* aW2        = (const float*)d_in[11];
    const float* ab2        = (const float*)d_in[12];
    float* out = (float*)d_out;
    (void)d_ws; (void)ws_size;   // no workspace needed: bins live in out[]

    const int E = in_sizes[1] / 2;
    const int A = in_sizes[3] / 3;
    const int N = in_sizes[0] / IC;

    // 1) clear out (doubles as clearing the u64 binning cells)
    const int zblocks = (out_size / 4 + 255) / 256;
    zero_kernel<<<zblocks, 256, 0, stream>>>(out, out_size);

    // 2) bin angles: 1 u64 atomic per angle into out-as-cells
    const int sblocks = (A + 255) / 256;
    angle_scatter<<<sblocks, 256, 0, stream>>>(angles, angle_index,
                                               aW1, ab1, (u64*)out, A);

    // 3) decode cells -> exact fp32 angle contribution, overwrite out rows
    const int gblocks = (N + 7) / 8;
    angle_gather<<<gblocks, 256, 0, stream>>>(out, aW1, ab1, aW2, ab2, N);

    // 4) expected-empty fixup for >PBIN realized pieces (uniform early-exit)
    angle_fixup<<<sblocks, 256, 0, stream>>>(angles, angle_index,
                                             aW1, ab1, aW2, ab2, out, A);

    // 5) edge branch accumulates on top via atomics
    edge_kernel<<<512, 256, 0, stream>>>(x, edge_index, edge_attr,
                                         eW1, eb1, eW2, eb2, out, E);
}

// Round 3
// 202.688 us; speedup vs baseline: 1.1706x; 1.1162x over previous
//
#include <hip/hip_runtime.h>
#include <hip/hip_bf16.h>
#include <stdint.h>

#define IC 32
#define OC 32
#define HID 32

// Angle binning: per node, PBIN u64 cells of (count << TSH | sum of t*2^20),
// stored IN-PLACE in the output buffer (one node row = 32 floats = 16 u64).
// count field: 20 bits (max 1M >= A=400k). t-sum: 44 bits (A*2^20 < 2^39).
#define PBIN 16
#define TSH 44
#define TSCALE 1048576.0f   // 2^20

typedef __attribute__((ext_vector_type(8))) _Float16 half8;
typedef __attribute__((ext_vector_type(4))) float f32x4;
typedef unsigned long long u64;

static __device__ __forceinline__ _Float16 f2h(float f) { return (_Float16)f; }

// ---------------------------------------------------------------------------
// Zero-init output (also clears the in-place binning cells)
// ---------------------------------------------------------------------------
__global__ void zero_kernel(float* __restrict__ out, int n) {
    int i = (blockIdx.x * blockDim.x + threadIdx.x) * 4;
    if (i + 3 < n) {
        *(float4*)(out + i) = make_float4(0.f, 0.f, 0.f, 0.f);
    } else {
        for (int k = i; k < n; ++k) out[k] = 0.f;
    }
}

// ---------------------------------------------------------------------------
// Angle stage 1: classify each angle onto its linear piece of
//   feat(t) = relu(t*aW1 + ab1) @ aW2 + ab2   (piecewise-linear in scalar t)
// Piece id c(t) = # hinges in their t->+inf state (monotone in t; equal c
// => identical relu mask => feat linear over the group). Accumulate
// (count, sum-of-t) per (node, piece) with ONE u64 atomic per angle,
// directly into out[] reinterpreted as u64 cells (cleared by zero_kernel).
// ---------------------------------------------------------------------------
__global__ __launch_bounds__(256) void angle_scatter(
    const float* __restrict__ angles, const int* __restrict__ angle_index,
    const float* __restrict__ aW1, const float* __restrict__ ab1,
    u64* __restrict__ cells, int A)
{
    float w1[HID], b1[HID];
#pragma unroll
    for (int k = 0; k < HID; ++k) { w1[k] = aW1[k]; b1[k] = ab1[k]; }

    int i0 = blockIdx.x * blockDim.x + threadIdx.x;
    int stride = gridDim.x * blockDim.x;
    for (int a = i0; a < A; a += stride) {
        const float t = angles[a];
        const int j = angle_index[A + a];   // center node
        int c = 0, c0 = 0;
#pragma unroll
        for (int k = 0; k < HID; ++k) {
            const bool pos = w1[k] > 0.f;
            const bool on  = fmaf(t, w1[k], b1[k]) > 0.f;
            const bool on0 = b1[k] > 0.f;
            c  += (pos ? on  : !on ) ? 1 : 0;
            c0 += (pos ? on0 : !on0) ? 1 : 0;
        }
        const int cc = c - c0;
        if ((unsigned)cc < (unsigned)PBIN) {
            const u64 enc = ((u64)1 << TSH) | (u64)(unsigned)(t * TSCALE);
            atomicAdd(cells + (size_t)j * PBIN + cc, enc);
        }
        // cc >= PBIN (requires >16 realized pieces) handled by angle_fixup
    }
}

// ---------------------------------------------------------------------------
// Angle stage 2: per node, decode its 16 cells and evaluate
//   sum_pieces cnt * feat(tsum/cnt)    (exact: feat linear on each piece,
//   and the group mean stays inside the piece interval).
// 2 nodes per wave (32 lanes = 32 output channels). Reads the node's own
// row as u64, then OVERWRITES it with the fp32 result.
// ---------------------------------------------------------------------------
__global__ __launch_bounds__(256) void angle_gather(
    float* __restrict__ out,
    const float* __restrict__ aW1, const float* __restrict__ ab1,
    const float* __restrict__ aW2, const float* __restrict__ ab2,
    int N)
{
    const int lane = threadIdx.x & 63;
    const int o    = lane & 31;
    const int half = lane >> 5;
    const int wib  = threadIdx.x >> 6;
    const int gw   = blockIdx.x * (blockDim.x >> 6) + wib;
    const int nodesPerIter = gridDim.x * (blockDim.x >> 6) * 2;

    float w1[HID], b1[HID], w2[HID];
#pragma unroll
    for (int k = 0; k < HID; ++k) {
        w1[k] = aW1[k];
        b1[k] = ab1[k];
        w2[k] = aW2[k * OC + o];
    }
    const float bias = ab2[o];

    for (int j = gw * 2 + half; j < N; j += nodesPerIter) {
        const u64* cj = (const u64*)out + (size_t)j * PBIN;
        float acc = 0.f, tot = 0.f;
#pragma unroll
        for (int cc = 0; cc < PBIN; ++cc) {
            const u64 v = cj[cc];
            if (v) {
                const float n  = (float)(unsigned)(v >> TSH);
                const float ts = (float)(v & (((u64)1 << TSH) - 1)) * (1.f / TSCALE);
                const float tb = ts / n;
                float s = 0.f;
#pragma unroll
                for (int k = 0; k < HID; ++k) {
                    float h = fmaf(tb, w1[k], b1[k]);
                    h = h > 0.f ? h : 0.f;
                    s = fmaf(h, w2[k], s);
                }
                acc = fmaf(n, s, acc);
                tot += n;
            }
        }
        out[(size_t)j * OC + o] = fmaf(tot, bias, acc);
    }
}

// ---------------------------------------------------------------------------
// Fixup for angles whose piece index exceeds PBIN (only possible if the
// weight draw realizes >16 pieces on t in [0,1); expected ZERO work --
// uniform early-exit). Runs AFTER gather, adds exact feat via atomics.
// ---------------------------------------------------------------------------
__global__ __launch_bounds__(256) void angle_fixup(
    const float* __restrict__ angles, const int* __restrict__ angle_index,
    const float* __restrict__ aW1, const float* __restrict__ ab1,
    const float* __restrict__ aW2, const float* __restrict__ ab2,
    float* __restrict__ out, int A)
{
    float w1[HID], b1[HID];
#pragma unroll
    for (int k = 0; k < HID; ++k) { w1[k] = aW1[k]; b1[k] = ab1[k]; }

    int c0 = 0, c1 = 0;
#pragma unroll
    for (int k = 0; k < HID; ++k) {
        const bool pos = w1[k] > 0.f;
        const bool f0 = pos ? (b1[k] > 0.f) : !(b1[k] > 0.f);
        const bool f1 = pos ? ((w1[k] + b1[k]) > 0.f) : !((w1[k] + b1[k]) > 0.f);
        c0 += f0 ? 1 : 0;
        c1 += f1 ? 1 : 0;
    }
    if (c1 - c0 + 1 <= PBIN) return;   // uniform: no overflow possible

    int i0 = blockIdx.x * blockDim.x + threadIdx.x;
    int stride = gridDim.x * blockDim.x;
    for (int a = i0; a < A; a += stride) {
        const float t = angles[a];
        const int j = angle_index[A + a];
        int c = 0;
#pragma unroll
        for (int k = 0; k < HID; ++k) {
            const bool pos = w1[k] > 0.f;
            const bool on  = fmaf(t, w1[k], b1[k]) > 0.f;
            c += (pos ? on : !on) ? 1 : 0;
        }
        if (c - c0 >= PBIN) {
            float h[HID];
#pragma unroll
            for (int k = 0; k < HID; ++k) {
                float v = fmaf(t, w1[k], b1[k]);
                h[k] = v > 0.f ? v : 0.f;
            }
            for (int o = 0; o < OC; ++o) {
                float s = ab2[o];
#pragma unroll
                for (int k = 0; k < HID; ++k) s = fmaf(h[k], aW2[k * OC + o], s);
                unsafeAtomicAdd(out + (size_t)j * OC + o, s);
            }
        }
    }
}

// ---------------------------------------------------------------------------
// Edge branch (round-0 structure, fragments switched bf16 -> f16):
//   Z(E x 1056) @ W2r(1056 x 32) via mfma_f32_16x16x32_f16, scatter-atomic.
// f16 A-frag build: x converted once per tile; per K-step a = xh * splat(hs)
// -> 4 v_pk_mul_f16 + 1 cvt + 1 pack (~8 VALU/step vs ~13 for bf16).
// Precision improves (f16 10-bit mantissa vs bf16 7-bit; |x*h| <= ~3).
// ---------------------------------------------------------------------------
__global__ __launch_bounds__(256) void edge_kernel(
    const float* __restrict__ x, const int* __restrict__ edge_index,
    const float* __restrict__ edge_attr,
    const float* __restrict__ eW1, const float* __restrict__ eb1,
    const float* __restrict__ eW2, const float* __restrict__ eb2,
    float* __restrict__ out, int E)
{
    const int tid   = threadIdx.x;
    const int lane  = tid & 63;
    const int gwave = blockIdx.x * 4 + (tid >> 6);
    const int ot    = gwave & 1;            // which 16-wide output tile
    const int tile0 = gwave >> 1;
    const int tstride = (gridDim.x * 4) >> 1;
    const int q     = lane >> 4;
    const int l15   = lane & 15;
    const int ocol  = ot * 16 + l15;

    // --- load B fragments once (register-resident across all edge tiles) ---
    half8 Bf[33];
#pragma unroll
    for (int s = 0; s < 32; ++s) {
        half8 b;
#pragma unroll
        for (int j = 0; j < 8; ++j)
            b[j] = f2h(eW2[s * 1024 + (q * 8 + j) * 32 + ocol]);
        Bf[s] = b;
    }
    {
        half8 b;
#pragma unroll
        for (int j = 0; j < 8; ++j)
            b[j] = f2h(eb2[(q * 8 + j) * 32 + ocol]);
        Bf[32] = b;
    }

    const int numTiles = (E + 15) >> 4;
    for (int tile = tile0; tile < numTiles; tile += tstride) {
        const int e16 = tile << 4;
        const int eA  = e16 + l15;
        const bool va = (eA < E);
        const int eAc = va ? eA : 0;
        const float t = va ? edge_attr[eAc] : 0.f;
        const int col = va ? edge_index[E + eAc] : 0;

        const float* xp = x + col * IC + q * 8;
        const float4 xlo = *(const float4*)(xp);
        const float4 xhi = *(const float4*)(xp + 4);

        // convert x fragment to f16 once per tile
        half8 xh;
        xh[0] = f2h(xlo.x); xh[1] = f2h(xlo.y);
        xh[2] = f2h(xlo.z); xh[3] = f2h(xlo.w);
        xh[4] = f2h(xhi.x); xh[5] = f2h(xhi.y);
        xh[6] = f2h(xhi.z); xh[7] = f2h(xhi.w);

        f32x4 acc = {0.f, 0.f, 0.f, 0.f};
#pragma unroll
        for (int s = 0; s < 32; ++s) {
            float hs = fmaf(t, eW1[s], eb1[s]);
            hs = hs > 0.f ? hs : 0.f;
            const _Float16 hh = f2h(hs);
            half8 hv = {hh, hh, hh, hh, hh, hh, hh, hh};
            half8 a = xh * hv;              // 4x v_pk_mul_f16
            acc = __builtin_amdgcn_mfma_f32_16x16x32_f16(a, Bf[s], acc, 0, 0, 0);
        }
        // bias K-step (h == 1): adds sum_i x_i * eb2[i*32+o]
        acc = __builtin_amdgcn_mfma_f32_16x16x32_f16(xh, Bf[32], acc, 0, 0, 0);

        // scatter: C row r holds edge e16 + q*4 + r, col = ocol
        const int ebase = e16 + q * 4;
#pragma unroll
        for (int r = 0; r < 4; ++r) {
            const int er = ebase + r;
            if (er < E) {
                const int dst = edge_index[er];   // row (destination node)
                unsafeAtomicAdd(out + (size_t)dst * OC + ocol, acc[r]);
            }
        }
    }
}

// ---------------------------------------------------------------------------
extern "C" void kernel_launch(void* const* d_in, const int* in_sizes, int n_in,
                              void* d_out, int out_size, void* d_ws, size_t ws_size,
                              hipStream_t stream)
{
    const float* x          = (const float*)d_in[0];
    const int*   edge_index = (const int*)d_in[1];
    const float* edge_attr  = (const float*)d_in[2];
    const int*   angle_index= (const int*)d_in[3];
    const float* angles     = (const float*)d_in[4];
    const float* eW1        = (const float*)d_in[5];
    const float* eb1        = (const float*)d_in[6];
    const float* eW2        = (const float*)d_in[7];
    const float* eb2        = (const float*)d_in[8];
    const float* aW1        = (const float*)d_in[9];
    const float* ab1        = (const float*)d_in[10];
    const float* aW2        = (const float*)d_in[11];
    const float* ab2        = (const float*)d_in[12];
    float* out = (float*)d_out;
    (void)d_ws; (void)ws_size;   // no workspace needed: bins live in out[]

    const int E = in_sizes[1] / 2;
    const int A = in_sizes[3] / 3;
    const int N = in_sizes[0] / IC;

    // 1) clear out (doubles as clearing the u64 binning cells)
    const int zblocks = (out_size / 4 + 255) / 256;
    zero_kernel<<<zblocks, 256, 0, stream>>>(out, out_size);

    // 2) bin angles: 1 u64 atomic per angle into out-as-cells
    const int sblocks = (A + 255) / 256;
    angle_scatter<<<sblocks, 256, 0, stream>>>(angles, angle_index,
                                               aW1, ab1, (u64*)out, A);

    // 3) decode cells -> exact fp32 angle contribution, overwrite out rows
    const int gblocks = (N + 7) / 8;
    angle_gather<<<gblocks, 256, 0, stream>>>(out, aW1, ab1, aW2, ab2, N);

    // 4) expected-empty fixup for >PBIN realized pieces (uniform early-exit)
    angle_fixup<<<sblocks, 256, 0, stream>>>(angles, angle_index,
                                             aW1, ab1, aW2, ab2, out, A);

    // 5) edge branch accumulates on top via atomics
    edge_kernel<<<512, 256, 0, stream>>>(x, edge_index, edge_attr,
                                         eW1, eb1, eW2, eb2, out, E);
}